// Round 6
// baseline (1218.188 us; speedup 1.0000x reference)
//
#include <hip/hip_runtime.h>

#define DD   121
#define NHID 15
#define NBLK 5
#define KS   11
#define IW   4096
#define OW   2043

// DPP row-rotate add: v += rotate_within_16(v, N). VALU-only 16-lane reduce.
#define ROR_ADD(v, N)                                                         \
  v += __int_as_float(__builtin_amdgcn_update_dpp(                            \
      0, __float_as_int(v), 0x120 + (N), 0xF, 0xF, true))

__device__ __forceinline__ void stage_weights(
    float* W1d, float* W2d, float* b2d, float* b1d,
    const float* __restrict__ W1, const float* __restrict__ W2,
    const float* __restrict__ b2, const float* __restrict__ b1,
    int blk, int t0, int nt)
{
    for (int i = t0; i < NHID * DD;     i += nt) W1d[i] = W1[blk*NHID*DD   + i];
    for (int i = t0; i < 2 * DD * NHID; i += nt) W2d[i] = W2[blk*2*DD*NHID + i];
    for (int i = t0; i < 2 * DD;        i += nt) b2d[i] = b2[blk*2*DD      + i];
    for (int i = t0; i < NHID;          i += nt) b1d[i] = b1[blk*NHID      + i];
}

// ---------------------------------------------------------------------------
// Flow inverse (MAF) + post-process. 2 waves: wave0 scans (lanes 0..15 active
// in the serial part, DPP reduction), wave1 prefetches next block's weights
// into the other LDS buffer (double-buffered).
// ---------------------------------------------------------------------------
__global__ __launch_bounds__(128) void flow_kernel(
    const float* __restrict__ kc,
    const float* __restrict__ W1, const float* __restrict__ b1,
    const float* __restrict__ W2, const float* __restrict__ b2,
    const float* __restrict__ lg, const float* __restrict__ beta,
    const float* __restrict__ mean, const float* __restrict__ var,
    float* __restrict__ kout)
{
    __shared__ float xs[DD];
    __shared__ float us[DD];
    __shared__ float W1s[2][NHID * DD];
    __shared__ float W2s[2][2 * DD * NHID + 16];  // +pad: lane15 reads 1 past row
    __shared__ float b2s[2][2 * DD];
    __shared__ float b1s[2][16];

    const int tid  = threadIdx.x;
    const int wv   = tid >> 6;
    const int lane = tid & 63;

    stage_weights(W1s[0], W2s[0], b2s[0], b1s[0], W1, W2, b2, b1, NBLK - 1, tid, 128);
    if (tid < DD) xs[tid] = kc[tid];
    __syncthreads();

    for (int b = NBLK - 1; b >= 0; --b) {
        const int buf = (NBLK - 1 - b) & 1;
        if (wv == 1) {
            if (b > 0)
                stage_weights(W1s[buf^1], W2s[buf^1], b2s[buf^1], b1s[buf^1],
                              W1, W2, b2, b1, b - 1, lane, 64);
        } else {
            // BatchNorm inverse (eval): x = (x-beta)*exp(-lg)*sqrt(var+eps)+mean
            for (int i = lane; i < DD; i += 64) {
                float s = sqrtf(var[b*DD + i] + 1e-5f);
                us[i] = (xs[i] - beta[b*DD + i]) * __expf(-lg[b*DD + i]) * s + mean[b*DD + i];
            }
            const int evenb = ((b & 1) == 0);
            if (lane < 16) {
                const int j = lane;
                float pre_h = (j < NHID) ? b1s[buf][j] : 0.f;
                for (int t = 0; t < DD; ++t) {
                    const int idx = evenb ? t : (DD - 1 - t);
                    // output mask: deg_in[idx] > dh[j]  <=>  t > j
                    float h  = (j < t && j < NHID) ? fmaxf(pre_h, 0.f) : 0.f;
                    float pm = h * W2s[buf][idx*NHID + j];
                    float pa = h * W2s[buf][(DD + idx)*NHID + j];
                    ROR_ADD(pm, 1); ROR_ADD(pa, 1);
                    ROR_ADD(pm, 2); ROR_ADD(pa, 2);
                    ROR_ADD(pm, 4); ROR_ADD(pa, 4);
                    ROR_ADD(pm, 8); ROR_ADD(pa, 8);
                    const float m  = pm + b2s[buf][idx];
                    const float la = pa + b2s[buf][DD + idx];
                    const float xv = fmaf(us[idx], __expf(la), m);
                    // hidden mask: dh[j] >= deg_in[idx]  <=>  j >= t
                    if (j >= t && j < NHID) pre_h = fmaf(xv, W1s[buf][j*DD + idx], pre_h);
                    if (j == 0) xs[idx] = xv;
                }
            }
        }
        __syncthreads();
    }

    // post-process: y = (sigmoid(x)-a)/(1-2a); k = y/sum(y)
    if (tid < 64) {
        const float A = 1e-6f;
        float y0, y1 = 0.f;
        {
            float v = xs[tid];
            y0 = (1.f / (1.f + __expf(-v)) - A) / (1.f - 2.f*A);
        }
        if (tid + 64 < DD) {
            float v = xs[tid + 64];
            y1 = (1.f / (1.f + __expf(-v)) - A) / (1.f - 2.f*A);
        }
        float s = y0 + y1;
        #pragma unroll
        for (int off = 32; off >= 1; off >>= 1) s += __shfl_xor(s, off, 64);
        kout[tid] = y0 / s;
        if (tid + 64 < DD) kout[tid + 64] = y1 / s;
    }
}

// ---------------------------------------------------------------------------
// 11x11 stride-2 valid conv, same kernel for all 3 channels.
// 256 threads -> 64x32 output tile. Input tile 137x73 in LDS, parity-split
// (stride-2 -> unit stride). SE=76: bank = (16ty+12rw+4tx)%32 -> 2-way (free).
// Weights read directly from global with uniform indices -> s_load/SGPR path.
// Staging: all loads issued to registers first (parallel), then LDS writes.
// ---------------------------------------------------------------------------
#define TIY 73
#define SE  76

__global__ __launch_bounds__(256, 3) void conv_kernel(
    const float* __restrict__ in, const float* __restrict__ kf,
    float* __restrict__ out)
{
    __shared__ __align__(16) float E[TIY * SE];
    __shared__ __align__(16) float O[TIY * SE];

    const int tid = threadIdx.x;
    const int cch = blockIdx.z;
    const int ox0 = blockIdx.x * 64;
    const int oy0 = blockIdx.y * 32;
    const int gx0 = ox0 * 2;          // multiple of 128 -> 16B-aligned rows
    const int gy0 = oy0 * 2;

    const float* __restrict__ inc = in + (size_t)cch * IW * IW;

    // ---- stage: issue all loads, then write all (breaks latency chain) ----
    {
        const int r0 = tid >> 5;
        const int l  = tid & 31;
        float4 g[10];
        float  tl[10];
        #pragma unroll
        for (int k = 0; k < 10; ++k) {
            const int r  = r0 + 8*k;
            const int gy = gy0 + r;
            g[k] = make_float4(0.f, 0.f, 0.f, 0.f);
            tl[k] = 0.f;
            if (r < TIY && gy < IW) {
                const float* rowp = inc + (size_t)gy * IW + gx0;
                g[k] = *(const float4*)(rowp + 4*l);          // cols 0..127 in-bounds
                if (l < 9 && (gx0 + 128 + l) < IW) tl[k] = rowp[128 + l];
            }
        }
        #pragma unroll
        for (int k = 0; k < 10; ++k) {
            const int r = r0 + 8*k;
            if (r < TIY) {
                *(float2*)&E[r*SE + 2*l] = make_float2(g[k].x, g[k].z);
                *(float2*)&O[r*SE + 2*l] = make_float2(g[k].y, g[k].w);
                if (l < 9) {
                    const int ct = 128 + l;
                    if (ct & 1) O[r*SE + (ct >> 1)] = tl[k];
                    else        E[r*SE + (ct >> 1)] = tl[k];
                }
            }
        }
    }
    __syncthreads();

    const int tx = tid & 15;
    const int ty = tid >> 4;

    float acc[2][4] = {{0.f,0.f,0.f,0.f},{0.f,0.f,0.f,0.f}};

    #pragma unroll
    for (int rw = 0; rw < 13; ++rw) {
        const int row = 4*ty + rw;
        const float4 ea = *(const float4*)&E[row*SE + 4*tx];
        const float4 eb = *(const float4*)&E[row*SE + 4*tx + 4];
        const float  ec =                  E[row*SE + 4*tx + 8];
        const float4 oa = *(const float4*)&O[row*SE + 4*tx];
        const float4 ob = *(const float4*)&O[row*SE + 4*tx + 4];
        const float ev[9] = {ea.x,ea.y,ea.z,ea.w,eb.x,eb.y,eb.z,eb.w,ec};
        const float ov[8] = {oa.x,oa.y,oa.z,oa.w,ob.x,ob.y,ob.z,ob.w};
        #pragma unroll
        for (int q = 0; q < 2; ++q) {
            const int ky = rw - 2*q;
            if (ky < 0 || ky > 10) continue;
            #pragma unroll
            for (int m = 0; m < 6; ++m) {
                const float we = kf[ky*KS + 2*m];     // uniform -> SGPR
                #pragma unroll
                for (int j = 0; j < 4; ++j)
                    acc[q][j] = fmaf(ev[m + j], we, acc[q][j]);
            }
            #pragma unroll
            for (int m = 0; m < 5; ++m) {
                const float wo = kf[ky*KS + 2*m + 1]; // uniform -> SGPR
                #pragma unroll
                for (int j = 0; j < 4; ++j)
                    acc[q][j] = fmaf(ov[m + j], wo, acc[q][j]);
            }
        }
    }

    const bool okx = (ox0 + 63) < OW;   // interior block in x: no per-j guard
    #pragma unroll
    for (int q = 0; q < 2; ++q) {
        const int oy = oy0 + 2*ty + q;
        if (oy >= OW) continue;
        const size_t base = ((size_t)cch * OW + oy) * OW;
        if (okx) {
            #pragma unroll
            for (int j = 0; j < 4; ++j)
                out[base + ox0 + 4*tx + j] = acc[q][j];
        } else {
            #pragma unroll
            for (int j = 0; j < 4; ++j) {
                const int ox = ox0 + 4*tx + j;
                if (ox < OW) out[base + ox] = acc[q][j];
            }
        }
    }
}

extern "C" void kernel_launch(void* const* d_in, const int* in_sizes, int n_in,
                              void* d_out, int out_size, void* d_ws, size_t ws_size,
                              hipStream_t stream)
{
    const float* in   = (const float*)d_in[0];
    const float* kc   = (const float*)d_in[1];
    const float* W1   = (const float*)d_in[2];
    const float* b1   = (const float*)d_in[3];
    const float* W2   = (const float*)d_in[4];
    const float* b2   = (const float*)d_in[5];
    const float* lg   = (const float*)d_in[6];
    const float* beta = (const float*)d_in[7];
    const float* mean = (const float*)d_in[8];
    const float* var  = (const float*)d_in[9];

    float* out  = (float*)d_out;
    float* kout = out + (size_t)3 * OW * OW;   // out_k lives at the tail of d_out

    flow_kernel<<<dim3(1), dim3(128), 0, stream>>>(kc, W1, b1, W2, b2, lg, beta, mean, var, kout);

    dim3 grid((OW + 63) / 64, (OW + 31) / 32, 3);
    conv_kernel<<<grid, dim3(256), 0, stream>>>(in, kout, out);
}

// Round 7
// 1078.441 us; speedup vs baseline: 1.1296x; 1.1296x over previous
//
#include <hip/hip_runtime.h>

#define DD   121
#define NHID 15
#define NBLK 5
#define KS   11
#define IW   4096
#define OW   2043

// DPP row-rotate add: v += rotate_within_16_lane_row(v, N). VALU-only reduce.
#define ROR_ADD(v, N)                                                         \
  v += __int_as_float(__builtin_amdgcn_update_dpp(                            \
      0, __float_as_int(v), 0x120 + (N), 0xF, 0xF, true))

__device__ __forceinline__ void stage_weights(
    float* W1d, float* W2d, float* b2d, float* b1d,
    const float* __restrict__ W1, const float* __restrict__ W2,
    const float* __restrict__ b2, const float* __restrict__ b1,
    int blk, int t0, int nt)
{
    for (int i = t0; i < NHID * DD;     i += nt) W1d[i] = W1[blk*NHID*DD   + i];
    for (int i = t0; i < 2 * DD * NHID; i += nt) W2d[i] = W2[blk*2*DD*NHID + i];
    for (int i = t0; i < 2 * DD;        i += nt) b2d[i] = b2[blk*2*DD      + i];
    for (int i = t0; i < NHID;          i += nt) b1d[i] = b1[blk*NHID      + i];
}

// ---------------------------------------------------------------------------
// Flow inverse (MAF) + post-process. 2 waves: wave0 scans (lanes 0..15 in the
// serial part, DPP reduction, operand prefetch for t+1 hides LDS latency),
// wave1 prefetches next block's weights into the other LDS buffer.
// ---------------------------------------------------------------------------
__global__ __launch_bounds__(128) void flow_kernel(
    const float* __restrict__ kc,
    const float* __restrict__ W1, const float* __restrict__ b1,
    const float* __restrict__ W2, const float* __restrict__ b2,
    const float* __restrict__ lg, const float* __restrict__ beta,
    const float* __restrict__ mean, const float* __restrict__ var,
    float* __restrict__ kout)
{
    __shared__ float xs[DD];
    __shared__ float us[DD];
    __shared__ float W1s[2][NHID * DD];
    __shared__ float W2s[2][2 * DD * NHID + 16];  // +pad: lane15 reads 1 past row
    __shared__ float b2s[2][2 * DD];
    __shared__ float b1s[2][16];

    const int tid  = threadIdx.x;
    const int wv   = tid >> 6;
    const int lane = tid & 63;

    stage_weights(W1s[0], W2s[0], b2s[0], b1s[0], W1, W2, b2, b1, NBLK - 1, tid, 128);
    if (tid < DD) xs[tid] = kc[tid];
    __syncthreads();

    for (int b = NBLK - 1; b >= 0; --b) {
        const int buf = (NBLK - 1 - b) & 1;
        if (wv == 1) {
            if (b > 0)
                stage_weights(W1s[buf^1], W2s[buf^1], b2s[buf^1], b1s[buf^1],
                              W1, W2, b2, b1, b - 1, lane, 64);
        } else {
            // BatchNorm inverse (eval): x = (x-beta)*exp(-lg)*sqrt(var+eps)+mean
            for (int i = lane; i < DD; i += 64) {
                float s = sqrtf(var[b*DD + i] + 1e-5f);
                us[i] = (xs[i] - beta[b*DD + i]) * __expf(-lg[b*DD + i]) * s + mean[b*DD + i];
            }
            const int evenb = ((b & 1) == 0);
            if (lane < 16) {
                const int j = lane;
                float pre_h = (j < NHID) ? b1s[buf][j] : 0.f;
                int   idx = evenb ? 0 : (DD - 1);
                float w2m = W2s[buf][idx*NHID + j];
                float w2a = W2s[buf][(DD + idx)*NHID + j];
                float w1v = W1s[buf][j*DD + idx];
                float uv  = us[idx];
                float c2m = b2s[buf][idx];
                float c2a = b2s[buf][DD + idx];
                for (int t = 0; t < DD; ++t) {
                    // prefetch step t+1 operands (hides LDS latency under reduce)
                    const int tn    = (t < DD - 1) ? (t + 1) : t;
                    const int idx_n = evenb ? tn : (DD - 1 - tn);
                    float w2m_n = W2s[buf][idx_n*NHID + j];
                    float w2a_n = W2s[buf][(DD + idx_n)*NHID + j];
                    float w1v_n = W1s[buf][j*DD + idx_n];
                    float uv_n  = us[idx_n];
                    float c2m_n = b2s[buf][idx_n];
                    float c2a_n = b2s[buf][DD + idx_n];
                    // output mask: t > j
                    float h  = (j < t && j < NHID) ? fmaxf(pre_h, 0.f) : 0.f;
                    float pm = h * w2m;
                    float pa = h * w2a;
                    ROR_ADD(pm, 1); ROR_ADD(pa, 1);
                    ROR_ADD(pm, 2); ROR_ADD(pa, 2);
                    ROR_ADD(pm, 4); ROR_ADD(pa, 4);
                    ROR_ADD(pm, 8); ROR_ADD(pa, 8);
                    const float m  = pm + c2m;
                    const float la = pa + c2a;
                    const float xv = fmaf(uv, __expf(la), m);
                    // hidden mask: j >= t
                    if (j >= t && j < NHID) pre_h = fmaf(xv, w1v, pre_h);
                    if (j == 0) xs[idx] = xv;
                    idx = idx_n; w2m = w2m_n; w2a = w2a_n;
                    w1v = w1v_n; uv = uv_n; c2m = c2m_n; c2a = c2a_n;
                }
            }
        }
        __syncthreads();
    }

    // post-process: y = (sigmoid(x)-a)/(1-2a); k = y/sum(y)
    if (tid < 64) {
        const float A = 1e-6f;
        float y0, y1 = 0.f;
        {
            float v = xs[tid];
            y0 = (1.f / (1.f + __expf(-v)) - A) / (1.f - 2.f*A);
        }
        if (tid + 64 < DD) {
            float v = xs[tid + 64];
            y1 = (1.f / (1.f + __expf(-v)) - A) / (1.f - 2.f*A);
        }
        float s = y0 + y1;
        #pragma unroll
        for (int off = 32; off >= 1; off >>= 1) s += __shfl_xor(s, off, 64);
        kout[tid] = y0 / s;
        if (tid + 64 < DD) kout[tid + 64] = y1 / s;
    }
}

// ---------------------------------------------------------------------------
// 11x11 stride-2 valid conv, same kernel for all 3 channels.
// 256 threads -> 64x32 output tile. Input tile 137x73 in LDS, parity-split
// (stride-2 -> unit stride). SE=72 (empirically lowest bank conflicts).
// Weights: uniform-index global reads -> scalar loads (SGPR), zero LDS traffic.
// Staging: round-5 interleaved per-row load->write (no big live arrays).
// ---------------------------------------------------------------------------
#define TIY 73
#define SE  72

__global__ __launch_bounds__(256, 3) void conv_kernel(
    const float* __restrict__ in, const float* __restrict__ kf,
    float* __restrict__ out)
{
    __shared__ __align__(16) float E[TIY * SE];
    __shared__ __align__(16) float O[TIY * SE];

    const int tid = threadIdx.x;
    const int cch = blockIdx.z;
    const int ox0 = blockIdx.x * 64;
    const int oy0 = blockIdx.y * 32;
    const int gx0 = ox0 * 2;          // multiple of 128 -> 16B-aligned rows
    const int gy0 = oy0 * 2;

    const float* __restrict__ inc = in + (size_t)cch * IW * IW;
    {
        const int l = tid & 31;
        const int c4 = l * 4;                      // cols 0..124 via float4
        for (int r = tid >> 5; r < TIY; r += 8) {
            const int gy = gy0 + r;
            const float* rowp = inc + (size_t)gy * IW + gx0;
            float4 g = make_float4(0.f, 0.f, 0.f, 0.f);
            if (gy < IW) g = *(const float4*)(rowp + c4);   // cols 0..127 in-bounds in x
            *(float2*)&E[r*SE + (c4 >> 1)] = make_float2(g.x, g.z);
            *(float2*)&O[r*SE + (c4 >> 1)] = make_float2(g.y, g.w);
            if (l < 9) {                           // tail cols 128..136 (guarded)
                const int ct = 128 + l;
                float v = 0.f;
                if (gy < IW && (gx0 + ct) < IW) v = rowp[ct];
                if (ct & 1) O[r*SE + (ct >> 1)] = v;
                else        E[r*SE + (ct >> 1)] = v;
            }
        }
    }
    __syncthreads();

    const int tx = tid & 15;
    const int ty = tid >> 4;

    float acc[2][4] = {{0.f,0.f,0.f,0.f},{0.f,0.f,0.f,0.f}};

    #pragma unroll
    for (int rw = 0; rw < 13; ++rw) {
        const int row = 4*ty + rw;
        const float4 ea = *(const float4*)&E[row*SE + 4*tx];
        const float4 eb = *(const float4*)&E[row*SE + 4*tx + 4];
        const float  ec =                  E[row*SE + 4*tx + 8];
        const float4 oa = *(const float4*)&O[row*SE + 4*tx];
        const float4 ob = *(const float4*)&O[row*SE + 4*tx + 4];
        const float ev[9] = {ea.x,ea.y,ea.z,ea.w,eb.x,eb.y,eb.z,eb.w,ec};
        const float ov[8] = {oa.x,oa.y,oa.z,oa.w,ob.x,ob.y,ob.z,ob.w};
        #pragma unroll
        for (int q = 0; q < 2; ++q) {
            const int ky = rw - 2*q;
            if (ky < 0 || ky > 10) continue;
            #pragma unroll
            for (int m = 0; m < 6; ++m) {
                const float we = kf[ky*KS + 2*m];     // uniform -> s_load/SGPR
                #pragma unroll
                for (int j = 0; j < 4; ++j)
                    acc[q][j] = fmaf(ev[m + j], we, acc[q][j]);
            }
            #pragma unroll
            for (int m = 0; m < 5; ++m) {
                const float wo = kf[ky*KS + 2*m + 1]; // uniform -> s_load/SGPR
                #pragma unroll
                for (int j = 0; j < 4; ++j)
                    acc[q][j] = fmaf(ov[m + j], wo, acc[q][j]);
            }
        }
    }

    const bool okx = (ox0 + 63) < OW;   // interior block in x: no per-j guard
    #pragma unroll
    for (int q = 0; q < 2; ++q) {
        const int oy = oy0 + 2*ty + q;
        if (oy >= OW) continue;
        const size_t base = ((size_t)cch * OW + oy) * OW;
        if (okx) {
            #pragma unroll
            for (int j = 0; j < 4; ++j)
                out[base + ox0 + 4*tx + j] = acc[q][j];
        } else {
            #pragma unroll
            for (int j = 0; j < 4; ++j) {
                const int ox = ox0 + 4*tx + j;
                if (ox < OW) out[base + ox] = acc[q][j];
            }
        }
    }
}

extern "C" void kernel_launch(void* const* d_in, const int* in_sizes, int n_in,
                              void* d_out, int out_size, void* d_ws, size_t ws_size,
                              hipStream_t stream)
{
    const float* in   = (const float*)d_in[0];
    const float* kc   = (const float*)d_in[1];
    const float* W1   = (const float*)d_in[2];
    const float* b1   = (const float*)d_in[3];
    const float* W2   = (const float*)d_in[4];
    const float* b2   = (const float*)d_in[5];
    const float* lg   = (const float*)d_in[6];
    const float* beta = (const float*)d_in[7];
    const float* mean = (const float*)d_in[8];
    const float* var  = (const float*)d_in[9];

    float* out  = (float*)d_out;
    float* kout = out + (size_t)3 * OW * OW;   // out_k lives at the tail of d_out

    flow_kernel<<<dim3(1), dim3(128), 0, stream>>>(kc, W1, b1, W2, b2, lg, beta, mean, var, kout);

    dim3 grid((OW + 63) / 64, (OW + 31) / 32, 3);
    conv_kernel<<<grid, dim3(256), 0, stream>>>(in, kout, out);
}

// Round 9
// 256.529 us; speedup vs baseline: 4.7487x; 4.2040x over previous
//
#include <hip/hip_runtime.h>

#define DD   121
#define NHID 15
#define NBLK 5
#define KS   11
#define IW   4096
#define OW   2043

// DPP row-rotate add: v += rotate_within_16_lane_row(v, N). VALU-only reduce.
#define ROR_ADD(v, N)                                                         \
  v += __int_as_float(__builtin_amdgcn_update_dpp(                            \
      0, __float_as_int(v), 0x120 + (N), 0xF, 0xF, true))

__device__ __forceinline__ void stage_weights(
    float* W1d, float* W2d, float* b2d, float* b1d,
    const float* __restrict__ W1, const float* __restrict__ W2,
    const float* __restrict__ b2, const float* __restrict__ b1,
    int blk, int t0, int nt)
{
    for (int i = t0; i < NHID * DD;     i += nt) W1d[i] = W1[blk*NHID*DD   + i];
    for (int i = t0; i < 2 * DD * NHID; i += nt) W2d[i] = W2[blk*2*DD*NHID + i];
    for (int i = t0; i < 2 * DD;        i += nt) b2d[i] = b2[blk*2*DD      + i];
    for (int i = t0; i < NHID;          i += nt) b1d[i] = b1[blk*NHID      + i];
}

// ---------------------------------------------------------------------------
// Flow inverse (MAF) + post-process. 2 waves: wave0 scans (lanes 0..15 in the
// serial part, DPP reduction, operand prefetch for t+1 hides LDS latency),
// wave1 prefetches next block's weights into the other LDS buffer.
// ---------------------------------------------------------------------------
__global__ __launch_bounds__(128) void flow_kernel(
    const float* __restrict__ kc,
    const float* __restrict__ W1, const float* __restrict__ b1,
    const float* __restrict__ W2, const float* __restrict__ b2,
    const float* __restrict__ lg, const float* __restrict__ beta,
    const float* __restrict__ mean, const float* __restrict__ var,
    float* __restrict__ kout)
{
    __shared__ float xs[DD];
    __shared__ float us[DD];
    __shared__ float W1s[2][NHID * DD];
    __shared__ float W2s[2][2 * DD * NHID + 16];  // +pad: lane15 reads 1 past row
    __shared__ float b2s[2][2 * DD];
    __shared__ float b1s[2][16];

    const int tid  = threadIdx.x;
    const int wv   = tid >> 6;
    const int lane = tid & 63;

    stage_weights(W1s[0], W2s[0], b2s[0], b1s[0], W1, W2, b2, b1, NBLK - 1, tid, 128);
    if (tid < DD) xs[tid] = kc[tid];
    __syncthreads();

    for (int b = NBLK - 1; b >= 0; --b) {
        const int buf = (NBLK - 1 - b) & 1;
        if (wv == 1) {
            if (b > 0)
                stage_weights(W1s[buf^1], W2s[buf^1], b2s[buf^1], b1s[buf^1],
                              W1, W2, b2, b1, b - 1, lane, 64);
        } else {
            // BatchNorm inverse (eval): x = (x-beta)*exp(-lg)*sqrt(var+eps)+mean
            for (int i = lane; i < DD; i += 64) {
                float s = sqrtf(var[b*DD + i] + 1e-5f);
                us[i] = (xs[i] - beta[b*DD + i]) * __expf(-lg[b*DD + i]) * s + mean[b*DD + i];
            }
            const int evenb = ((b & 1) == 0);
            if (lane < 16) {
                const int j = lane;
                float pre_h = (j < NHID) ? b1s[buf][j] : 0.f;
                int   idx = evenb ? 0 : (DD - 1);
                float w2m = W2s[buf][idx*NHID + j];
                float w2a = W2s[buf][(DD + idx)*NHID + j];
                float w1v = W1s[buf][j*DD + idx];
                float uv  = us[idx];
                float c2m = b2s[buf][idx];
                float c2a = b2s[buf][DD + idx];
                for (int t = 0; t < DD; ++t) {
                    // prefetch step t+1 operands (hides LDS latency under reduce)
                    const int tn    = (t < DD - 1) ? (t + 1) : t;
                    const int idx_n = evenb ? tn : (DD - 1 - tn);
                    float w2m_n = W2s[buf][idx_n*NHID + j];
                    float w2a_n = W2s[buf][(DD + idx_n)*NHID + j];
                    float w1v_n = W1s[buf][j*DD + idx_n];
                    float uv_n  = us[idx_n];
                    float c2m_n = b2s[buf][idx_n];
                    float c2a_n = b2s[buf][DD + idx_n];
                    // output mask: t > j
                    float h  = (j < t && j < NHID) ? fmaxf(pre_h, 0.f) : 0.f;
                    float pm = h * w2m;
                    float pa = h * w2a;
                    ROR_ADD(pm, 1); ROR_ADD(pa, 1);
                    ROR_ADD(pm, 2); ROR_ADD(pa, 2);
                    ROR_ADD(pm, 4); ROR_ADD(pa, 4);
                    ROR_ADD(pm, 8); ROR_ADD(pa, 8);
                    const float m  = pm + c2m;
                    const float la = pa + c2a;
                    const float xv = fmaf(uv, __expf(la), m);
                    // hidden mask: j >= t
                    if (j >= t && j < NHID) pre_h = fmaf(xv, w1v, pre_h);
                    if (j == 0) xs[idx] = xv;
                    idx = idx_n; w2m = w2m_n; w2a = w2a_n;
                    w1v = w1v_n; uv = uv_n; c2m = c2m_n; c2a = c2a_n;
                }
            }
        }
        __syncthreads();
    }

    // post-process: y = (sigmoid(x)-a)/(1-2a); k = y/sum(y)
    if (tid < 64) {
        const float A = 1e-6f;
        float y0, y1 = 0.f;
        {
            float v = xs[tid];
            y0 = (1.f / (1.f + __expf(-v)) - A) / (1.f - 2.f*A);
        }
        if (tid + 64 < DD) {
            float v = xs[tid + 64];
            y1 = (1.f / (1.f + __expf(-v)) - A) / (1.f - 2.f*A);
        }
        float s = y0 + y1;
        #pragma unroll
        for (int off = 32; off >= 1; off >>= 1) s += __shfl_xor(s, off, 64);
        kout[tid] = y0 / s;
        if (tid + 64 < DD) kout[tid + 64] = y1 / s;
    }
}

// ---------------------------------------------------------------------------
// 11x11 stride-2 valid conv, same kernel for all 3 channels.
// 256 threads -> 64x16 output tile (each thread 4x1). Input tile 137x41 in
// LDS, parity-split by column (stride-2 -> unit stride). LDS 23.6 KB/block
// -> 4-6 blocks/CU (vs 2 at the old 43 KB tile): latency hiding via TLP.
// Weights: uniform-index global reads -> scalar loads (SGPR).
// NO launch_bounds min-waves (a forced cap caused catastrophic spills, r6/r7).
// ---------------------------------------------------------------------------
#define TIY 41
#define SE  72

__global__ __launch_bounds__(256) void conv_kernel(
    const float* __restrict__ in, const float* __restrict__ kf,
    float* __restrict__ out)
{
    __shared__ __align__(16) float E[TIY * SE];
    __shared__ __align__(16) float O[TIY * SE];

    const int tid = threadIdx.x;
    const int cch = blockIdx.z;
    const int ox0 = blockIdx.x * 64;
    const int oy0 = blockIdx.y * 16;
    const int gx0 = ox0 * 2;          // multiple of 128 -> 16B-aligned rows
    const int gy0 = oy0 * 2;

    const float* __restrict__ inc = in + (size_t)cch * IW * IW;
    {
        const int l  = tid & 31;
        const int c4 = l * 4;                      // cols 0..127 via float4
        for (int r = tid >> 5; r < TIY; r += 8) {
            const int gy = gy0 + r;
            const float* rowp = inc + (size_t)gy * IW + gx0;
            float4 g = make_float4(0.f, 0.f, 0.f, 0.f);
            if (gy < IW) g = *(const float4*)(rowp + c4);   // cols 0..127 in-bounds in x
            *(float2*)&E[r*SE + (c4 >> 1)] = make_float2(g.x, g.z);
            *(float2*)&O[r*SE + (c4 >> 1)] = make_float2(g.y, g.w);
            if (l < 9) {                           // tail cols 128..136 (guarded)
                const int ct = 128 + l;
                float v = 0.f;
                if (gy < IW && (gx0 + ct) < IW) v = rowp[ct];
                if (ct & 1) O[r*SE + (ct >> 1)] = v;
                else        E[r*SE + (ct >> 1)] = v;
            }
        }
    }
    __syncthreads();

    const int tx = tid & 15;
    const int ty = tid >> 4;

    float acc[4] = {0.f, 0.f, 0.f, 0.f};

    #pragma unroll
    for (int ky = 0; ky < 11; ++ky) {
        const int row = 2*ty + ky;
        const float4 ea = *(const float4*)&E[row*SE + 4*tx];
        const float4 eb = *(const float4*)&E[row*SE + 4*tx + 4];
        const float  ec =                  E[row*SE + 4*tx + 8];
        const float4 oa = *(const float4*)&O[row*SE + 4*tx];
        const float4 ob = *(const float4*)&O[row*SE + 4*tx + 4];
        const float ev[9] = {ea.x,ea.y,ea.z,ea.w,eb.x,eb.y,eb.z,eb.w,ec};
        const float ov[8] = {oa.x,oa.y,oa.z,oa.w,ob.x,ob.y,ob.z,ob.w};
        #pragma unroll
        for (int m = 0; m < 6; ++m) {
            const float we = kf[ky*KS + 2*m];     // uniform -> s_load/SGPR
            #pragma unroll
            for (int j = 0; j < 4; ++j)
                acc[j] = fmaf(ev[m + j], we, acc[j]);
        }
        #pragma unroll
        for (int m = 0; m < 5; ++m) {
            const float wo = kf[ky*KS + 2*m + 1]; // uniform -> s_load/SGPR
            #pragma unroll
            for (int j = 0; j < 4; ++j)
                acc[j] = fmaf(ov[m + j], wo, acc[j]);
        }
    }

    const int oy = oy0 + ty;
    if (oy < OW) {
        const size_t base = ((size_t)cch * OW + oy) * OW;
        if ((ox0 + 63) < OW) {
            #pragma unroll
            for (int j = 0; j < 4; ++j)
                out[base + ox0 + 4*tx + j] = acc[j];
        } else {
            #pragma unroll
            for (int j = 0; j < 4; ++j) {
                const int ox = ox0 + 4*tx + j;
                if (ox < OW) out[base + ox] = acc[j];
            }
        }
    }
}

extern "C" void kernel_launch(void* const* d_in, const int* in_sizes, int n_in,
                              void* d_out, int out_size, void* d_ws, size_t ws_size,
                              hipStream_t stream)
{
    const float* in   = (const float*)d_in[0];
    const float* kc   = (const float*)d_in[1];
    const float* W1   = (const float*)d_in[2];
    const float* b1   = (const float*)d_in[3];
    const float* W2   = (const float*)d_in[4];
    const float* b2   = (const float*)d_in[5];
    const float* lg   = (const float*)d_in[6];
    const float* beta = (const float*)d_in[7];
    const float* mean = (const float*)d_in[8];
    const float* var  = (const float*)d_in[9];

    float* out  = (float*)d_out;
    float* kout = out + (size_t)3 * OW * OW;   // out_k lives at the tail of d_out

    flow_kernel<<<dim3(1), dim3(128), 0, stream>>>(kc, W1, b1, W2, b2, lg, beta, mean, var, kout);

    dim3 grid((OW + 63) / 64, (OW + 15) / 16, 3);
    conv_kernel<<<grid, dim3(256), 0, stream>>>(in, kout, out);
}